// Round 5
// baseline (271.001 us; speedup 1.0000x reference)
//
#include <hip/hip_runtime.h>
#include <hip/hip_bf16.h>

// B=8192 rows, N=4096 omegas/row, W=1000 bins, L=101 Legendre terms.
// Exact simplifications (verified r3):
//   * pdf normalization cancels in grad/pdf -> skipped
//   * sigma<=0.6 rows are pure elementwise -omega/sigma^2
//   * series terms beyond l=16 underflow for sigma>0.6 -> fixed L=17 unroll
// Round-5 structure (block-churn/MLP theory): r4 proved table build is free
// (split gather == combined main == 79us) -> bottleneck is the stream+gather
// core's shallow memory pipeline + 8192 short-lived blocks. Now: ROWS_PB=4
// rows per block (grid 2048), fully unrolled; next row's omega loads +
// table build issue BEFORE current row's gather (latency hidden under it);
// stores drain under the next row's compute. Shifted-table layout restored
// (ds_read2_b32 pair per element instead of 2 independent ds_read_b32).

#define L_TERMS 101
#define W_BINS 1000
#define N_COLS 4096
#define TPB 256
#define ROWS_PB 4
#define TRANS_STRIDE 1024   // padded transpose row stride
#define PAD_W 1004          // shifted pdf table: tab[k] = p[k-1], k=1..1000
#define GRAD_T 0.6f
#define L_FIX 17            // fixed term count, exact for sigma > 0.6

typedef float v4f __attribute__((ext_vector_type(4)));

// ---------------------------------------------------------------------------
// Transpose sine_terms [1000][101] -> sine_t [101][1024] (padded)
__global__ __launch_bounds__(128) void transpose_sine(
    const float* __restrict__ sine, float* __restrict__ sine_t) {
  int w = blockIdx.x;   // 0..999
  int t = threadIdx.x;  // 0..127
  if (t < L_TERMS) sine_t[(size_t)t * TRANS_STRIDE + w] = sine[(size_t)w * L_TERMS + t];
}

// ---------------------------------------------------------------------------
__device__ __forceinline__ void build_acc(float s, const float* __restrict__ sine_t,
                                          int w0, float acc[4]) {
  float e[L_FIX];
  const float ns2 = -0.5f * s * s;
#pragma unroll
  for (int l = 0; l < L_FIX; ++l) e[l] = __expf(ns2 * (float)(l * (l + 1)));
  acc[0] = acc[1] = acc[2] = acc[3] = 0.0f;
#pragma unroll
  for (int l = 0; l < L_FIX; ++l) {
    v4f sv = *(const v4f*)(sine_t + (size_t)l * TRANS_STRIDE + w0);
    acc[0] = fmaf(e[l], sv.x, acc[0]);
    acc[1] = fmaf(e[l], sv.y, acc[1]);
    acc[2] = fmaf(e[l], sv.z, acc[2]);
    acc[3] = fmaf(e[l], sv.w, acc[3]);
  }
}

// ---------------------------------------------------------------------------
// Main: 4 rows per block, software-pipelined across rows.
__global__ __launch_bounds__(TPB, 4) void igso3_multi(
    const float* __restrict__ sigmas,
    const float* __restrict__ omegas,
    const float* __restrict__ omega_grid,
    const float* __restrict__ sine_t,   // [101][1024]
    float* __restrict__ out, int Btot) {
  __shared__ float s_pdf[PAD_W];   // tab[k]=p[k-1]; tab[0]=p[0], tab[1001]=p[998]

  const int tid = threadIdx.x;
  const int w0 = tid * 4;
  const float bw = omega_grid[1] - omega_grid[0];
  const float inv_bw = 1.0f / bw;

  const int row0 = blockIdx.x * ROWS_PB;

  // ---- prologue: row 0 state ----
  float s_cur = sigmas[row0];
  bool ser_cur = s_cur > GRAD_T;
  v4f om_cur[4];
  {
    const v4f* omp = (const v4f*)(omegas + (size_t)row0 * N_COLS);
#pragma unroll
    for (int k = 0; k < 4; ++k) om_cur[k] = omp[k * TPB + tid];
  }
  float acc_cur[4];
  if (ser_cur) build_acc(s_cur, sine_t, w0, acc_cur);

#pragma unroll
  for (int i = 0; i < ROWS_PB; ++i) {
    const int row = row0 + i;
    v4f* out4 = (v4f*)(out + (size_t)row * N_COLS);

    // stage current table (block-uniform branch -> uniform barrier)
    if (ser_cur) {
      if (w0 < W_BINS) {
#pragma unroll
        for (int j = 0; j < 4; ++j) s_pdf[w0 + 1 + j] = acc_cur[j];
        if (tid == 0) s_pdf[0] = acc_cur[0];        // pad left  = p[0]
        if (w0 == 996) s_pdf[1001] = acc_cur[2];    // pad right = p[998]
      }
      __syncthreads();
    }

    // issue NEXT row's loads + build its table coefficients: these L2/HBM
    // loads fly while the gather below runs (results consumed next iter).
    float s_next = 0.0f;
    bool ser_next = false;
    v4f om_next[4];
    float acc_next[4];
    if (i + 1 < ROWS_PB && row + 1 < Btot) {
      s_next = sigmas[row + 1];
      ser_next = s_next > GRAD_T;
      const v4f* omp = (const v4f*)(omegas + (size_t)(row + 1) * N_COLS);
#pragma unroll
      for (int k = 0; k < 4; ++k) om_next[k] = omp[k * TPB + tid];
      if (ser_next) build_acc(s_next, sine_t, w0, acc_next);
    }

    // process current row
    if (ser_cur) {
#pragma unroll
      for (int k = 0; k < 4; ++k) {
        float o[4] = {om_cur[k].x, om_cur[k].y, om_cur[k].z, om_cur[k].w};
        float rv[4];
#pragma unroll
        for (int j = 0; j < 4; ++j) {
          // omega >= 0 -> int-cast == floor; idx in [0,1000]
          int idx = (int)fmaf(o[j], inv_bw, 0.5f);
          idx = min(idx, 1000);
          float shift = fmaf(-((float)idx + 0.5f), bw, o[j]);
          float left  = s_pdf[idx];        // ds_read2_b32 pair
          float right = s_pdf[idx + 1];
          float grad = (right - left) * inv_bw;
          float accu = fmaf(shift, grad, left);
          rv[j] = grad * __builtin_amdgcn_rcpf(accu);
        }
        v4f res = {rv[0], rv[1], rv[2], rv[3]};
        __builtin_nontemporal_store(res, &out4[k * TPB + tid]);
      }
      __syncthreads();   // all reads of s_pdf done before next row's ds_write
    } else {
      const float inv_s2 = __builtin_amdgcn_rcpf(s_cur * s_cur);
#pragma unroll
      for (int k = 0; k < 4; ++k) {
        v4f r = om_cur[k] * (-inv_s2);
        __builtin_nontemporal_store(r, &out4[k * TPB + tid]);
      }
    }

    // rotate pipeline state (unrolled -> pure register renaming)
    s_cur = s_next;
    ser_cur = ser_next;
#pragma unroll
    for (int k = 0; k < 4; ++k) om_cur[k] = om_next[k];
#pragma unroll
    for (int j = 0; j < 4; ++j) acc_cur[j] = acc_next[j];
  }
}

// ---------------------------------------------------------------------------
// Fallback (no workspace): round-3-verified combined kernel, untransposed.
__global__ __launch_bounds__(TPB, 6) void igso3_main_nt(
    const float* __restrict__ sigmas,
    const float* __restrict__ omegas,
    const float* __restrict__ omega_grid,
    const float* __restrict__ sine_src,  // [1000][101]
    float* __restrict__ out) {
  __shared__ float s_pdf[PAD_W];

  const int tid = threadIdx.x;
  const int b = blockIdx.x;

  const v4f* __restrict__ om4 = (const v4f*)(omegas + (size_t)b * N_COLS);
  v4f* __restrict__ out4 = (v4f*)(out + (size_t)b * N_COLS);

  v4f om[4];
#pragma unroll
  for (int k = 0; k < 4; ++k) om[k] = om4[k * TPB + tid];

  const float s = sigmas[b];
  const float bw = omega_grid[1] - omega_grid[0];
  const float inv_bw = 1.0f / bw;

  if (s <= GRAD_T) {
    const float inv_s2 = __builtin_amdgcn_rcpf(s * s);
#pragma unroll
    for (int k = 0; k < 4; ++k) {
      v4f r = om[k] * (-inv_s2);
      __builtin_nontemporal_store(r, &out4[k * TPB + tid]);
    }
    return;
  }

  float e[L_FIX];
  const float ns2 = -0.5f * s * s;
#pragma unroll
  for (int l = 0; l < L_FIX; ++l) e[l] = __expf(ns2 * (float)(l * (l + 1)));

  const int w0 = tid * 4;
  float acc[4] = {0.0f, 0.0f, 0.0f, 0.0f};
  if (w0 < W_BINS) {
#pragma unroll
    for (int l = 0; l < L_FIX; ++l) {
#pragma unroll
      for (int j = 0; j < 4; ++j)
        acc[j] = fmaf(e[l], sine_src[(size_t)(w0 + j) * L_TERMS + l], acc[j]);
    }
#pragma unroll
    for (int j = 0; j < 4; ++j) s_pdf[w0 + 1 + j] = acc[j];
    if (tid == 0) s_pdf[0] = acc[0];
    if (w0 == 996) s_pdf[1001] = acc[2];
  }
  __syncthreads();

#pragma unroll
  for (int k = 0; k < 4; ++k) {
    float o[4] = {om[k].x, om[k].y, om[k].z, om[k].w};
    float rv[4];
#pragma unroll
    for (int j = 0; j < 4; ++j) {
      int idx = (int)fmaf(o[j], inv_bw, 0.5f);
      idx = min(idx, 1000);
      float shift = fmaf(-((float)idx + 0.5f), bw, o[j]);
      float left  = s_pdf[idx];
      float right = s_pdf[idx + 1];
      float grad = (right - left) * inv_bw;
      float accu = fmaf(shift, grad, left);
      rv[j] = grad * __builtin_amdgcn_rcpf(accu);
    }
    v4f res = {rv[0], rv[1], rv[2], rv[3]};
    __builtin_nontemporal_store(res, &out4[k * TPB + tid]);
  }
}

// ---------------------------------------------------------------------------
extern "C" void kernel_launch(void* const* d_in, const int* in_sizes, int n_in,
                              void* d_out, int out_size, void* d_ws, size_t ws_size,
                              hipStream_t stream) {
  const float* sigmas     = (const float*)d_in[0];
  const float* omegas     = (const float*)d_in[1];
  const float* omega_grid = (const float*)d_in[2];
  // d_in[3] = ls (unused)
  const float* sine_terms = (const float*)d_in[4];
  float* out = (float*)d_out;

  const int B = in_sizes[0];  // 8192

  const size_t trans_bytes = (size_t)L_TERMS * TRANS_STRIDE * sizeof(float); // 404 KB

  if (ws_size >= trans_bytes) {
    float* sine_t = (float*)d_ws;
    transpose_sine<<<W_BINS, 128, 0, stream>>>(sine_terms, sine_t);
    const int grid = (B + ROWS_PB - 1) / ROWS_PB;   // 2048
    igso3_multi<<<grid, TPB, 0, stream>>>(sigmas, omegas, omega_grid,
                                          sine_t, out, B);
  } else {
    igso3_main_nt<<<B, TPB, 0, stream>>>(sigmas, omegas, omega_grid,
                                         sine_terms, out);
  }
}

// Round 6
// 263.353 us; speedup vs baseline: 1.0290x; 1.0290x over previous
//
#include <hip/hip_runtime.h>
#include <hip/hip_bf16.h>

// B=8192 rows, N=4096 omegas/row, W=1000 bins, L=101 Legendre terms.
// Exact simplifications (verified r3/r4):
//   * pdf normalization cancels in grad/pdf -> skipped
//   * sigma<=0.6 rows are pure elementwise -omega/sigma^2
//   * series terms beyond l=16 underflow for sigma>0.6 -> fixed L=17 unroll
// Round-6 theory: r3/r4/r5 pin the bottleneck on the __syncthreads after
// the LDS table write -- the compiler emits s_waitcnt vmcnt(0) before
// s_barrier, force-draining the hoisted omega loads; during the whole
// gather/store tail a block has ~0 outstanding reads (Little's law ->
// ~2.5 TB/s observed). Fix: NO BARRIER AT ALL. Each WAVE stages the full
// 4KB table into its own private LDS region (s_tab[wave][1024]); the
// ds_write->ds_read ordering is same-wave lgkmcnt only. Table loads issue
// oldest, om loads stay in flight through staging and gather.
// Pad handling via clamp arithmetic (verified r4):
//   left  = pdf_pad[idx]   == p[max(idx-1,0)]
//   right = pdf_pad[idx+1] == p[idx>=1000 ? 998 : idx]

#define L_TERMS 101
#define W_BINS 1000
#define N_COLS 4096
#define TPB 256
#define TRANS_STRIDE 1024   // padded transpose row stride
#define TAB_STRIDE 1024     // floats per pdf-table row in workspace
#define PAD_W 1004          // (fallback kernel only)
#define GRAD_T 0.6f
#define L_FIX 17            // fixed term count, exact for sigma > 0.6

typedef float v4f __attribute__((ext_vector_type(4)));

// ---------------------------------------------------------------------------
// Transpose sine_terms [1000][101] -> sine_t [101][1024] (padded)
__global__ __launch_bounds__(128) void transpose_sine(
    const float* __restrict__ sine, float* __restrict__ sine_t) {
  int w = blockIdx.x;   // 0..999
  int t = threadIdx.x;  // 0..127
  if (t < L_TERMS) sine_t[(size_t)t * TRANS_STRIDE + w] = sine[(size_t)w * L_TERMS + t];
}

// ---------------------------------------------------------------------------
// Kernel A: per series-row pdf table -> tabs[b][0..999] (aligned stores).
// Verified in r4.
__global__ __launch_bounds__(TPB, 6) void build_tables(
    const float* __restrict__ sigmas,
    const float* __restrict__ sine_t,   // [101][1024]
    float* __restrict__ tabs) {         // [B][1024]
  const int b = blockIdx.x;
  const float s = sigmas[b];
  if (s <= GRAD_T) return;              // gaussian row: no table needed

  const int tid = threadIdx.x;
  const int w0 = tid * 4;
  if (w0 >= W_BINS) return;

  float e[L_FIX];
  const float ns2 = -0.5f * s * s;
#pragma unroll
  for (int l = 0; l < L_FIX; ++l)
    e[l] = __expf(ns2 * (float)(l * (l + 1)));

  float acc[4] = {0.0f, 0.0f, 0.0f, 0.0f};
#pragma unroll
  for (int l = 0; l < L_FIX; ++l) {
    v4f sv = *(const v4f*)(sine_t + (size_t)l * TRANS_STRIDE + w0);
    acc[0] = fmaf(e[l], sv.x, acc[0]);
    acc[1] = fmaf(e[l], sv.y, acc[1]);
    acc[2] = fmaf(e[l], sv.z, acc[2]);
    acc[3] = fmaf(e[l], sv.w, acc[3]);
  }
  v4f r = {acc[0], acc[1], acc[2], acc[3]};
  *(v4f*)(tabs + (size_t)b * TAB_STRIDE + w0) = r;   // cached store: B reads it next
}

// ---------------------------------------------------------------------------
// Kernel B: barrier-free streamer. Each wave stages the 4KB table into its
// OWN LDS region; loads stay in flight through staging + gather.
__global__ __launch_bounds__(TPB, 6) void igso3_gather(
    const float* __restrict__ sigmas,
    const float* __restrict__ omegas,
    const float* __restrict__ omega_grid,
    const float* __restrict__ tabs,
    float* __restrict__ out) {
  __shared__ float s_tab[4][TAB_STRIDE];   // wave-private 4KB tables

  const int tid = threadIdx.x;
  const int wv  = tid >> 6;    // wave 0..3
  const int ln  = tid & 63;    // lane
  const int b = blockIdx.x;
  const float s = sigmas[b];
  const bool ser = s > GRAD_T;

  const v4f* __restrict__ om4 = (const v4f*)(omegas + (size_t)b * N_COLS);
  v4f* __restrict__ out4 = (v4f*)(out + (size_t)b * N_COLS);

  // Table loads FIRST (oldest in vmem queue): the ds_write below waits only
  // on these (vmcnt(4)), leaving the om loads in flight.
  v4f tv[4];
  if (ser) {
    const float* tb = tabs + (size_t)b * TAB_STRIDE;
#pragma unroll
    for (int k = 0; k < 4; ++k) tv[k] = *(const v4f*)(tb + k * 256 + ln * 4);
  }

  v4f om[4];
#pragma unroll
  for (int k = 0; k < 4; ++k) om[k] = om4[k * TPB + tid];

  const float bw = omega_grid[1] - omega_grid[0];
  const float inv_bw = 1.0f / bw;

  if (!ser) {
    const float inv_s2 = __builtin_amdgcn_rcpf(s * s);
#pragma unroll
    for (int k = 0; k < 4; ++k) {
      v4f r = om[k] * (-inv_s2);
      __builtin_nontemporal_store(r, &out4[k * TPB + tid]);
    }
    return;
  }

  // Wave-private staging: linear b128 writes, conflict-free. No barrier --
  // same-wave ds ordering via lgkmcnt only.
  float* mytab = s_tab[wv];
#pragma unroll
  for (int k = 0; k < 4; ++k) *(v4f*)(mytab + k * 256 + ln * 4) = tv[k];

#pragma unroll
  for (int k = 0; k < 4; ++k) {
    float o[4] = {om[k].x, om[k].y, om[k].z, om[k].w};
    float rv[4];
#pragma unroll
    for (int j = 0; j < 4; ++j) {
      // omega >= 0 -> int-cast == floor; idx in [0,1000]
      int idx = (int)fmaf(o[j], inv_bw, 0.5f);
      idx = min(idx, 1000);
      float shift = fmaf(-((float)idx + 0.5f), bw, o[j]);
      int il = max(idx - 1, 0);               // pdf_pad[idx]
      int ir = (idx >= 1000) ? 998 : idx;     // pdf_pad[idx+1]
      float left  = mytab[il];
      float right = mytab[ir];
      float grad = (right - left) * inv_bw;
      float accu = fmaf(shift, grad, left);
      rv[j] = grad * __builtin_amdgcn_rcpf(accu);
    }
    v4f res = {rv[0], rv[1], rv[2], rv[3]};
    __builtin_nontemporal_store(res, &out4[k * TPB + tid]);
  }
}

// ---------------------------------------------------------------------------
// Fallback (no workspace): r3-verified combined kernel, untransposed input.
__global__ __launch_bounds__(TPB, 6) void igso3_main_nt(
    const float* __restrict__ sigmas,
    const float* __restrict__ omegas,
    const float* __restrict__ omega_grid,
    const float* __restrict__ sine_src,  // [1000][101]
    float* __restrict__ out) {
  __shared__ float s_pdf[PAD_W];

  const int tid = threadIdx.x;
  const int b = blockIdx.x;

  const v4f* __restrict__ om4 = (const v4f*)(omegas + (size_t)b * N_COLS);
  v4f* __restrict__ out4 = (v4f*)(out + (size_t)b * N_COLS);

  v4f om[4];
#pragma unroll
  for (int k = 0; k < 4; ++k) om[k] = om4[k * TPB + tid];

  const float s = sigmas[b];
  const float bw = omega_grid[1] - omega_grid[0];
  const float inv_bw = 1.0f / bw;

  if (s <= GRAD_T) {
    const float inv_s2 = __builtin_amdgcn_rcpf(s * s);
#pragma unroll
    for (int k = 0; k < 4; ++k) {
      v4f r = om[k] * (-inv_s2);
      __builtin_nontemporal_store(r, &out4[k * TPB + tid]);
    }
    return;
  }

  float e[L_FIX];
  const float ns2 = -0.5f * s * s;
#pragma unroll
  for (int l = 0; l < L_FIX; ++l) e[l] = __expf(ns2 * (float)(l * (l + 1)));

  const int w0 = tid * 4;
  float acc[4] = {0.0f, 0.0f, 0.0f, 0.0f};
  if (w0 < W_BINS) {
#pragma unroll
    for (int l = 0; l < L_FIX; ++l) {
#pragma unroll
      for (int j = 0; j < 4; ++j)
        acc[j] = fmaf(e[l], sine_src[(size_t)(w0 + j) * L_TERMS + l], acc[j]);
    }
#pragma unroll
    for (int j = 0; j < 4; ++j) s_pdf[w0 + 1 + j] = acc[j];
    if (tid == 0) s_pdf[0] = acc[0];
    if (w0 == 996) s_pdf[1001] = acc[2];
  }
  __syncthreads();

#pragma unroll
  for (int k = 0; k < 4; ++k) {
    float o[4] = {om[k].x, om[k].y, om[k].z, om[k].w};
    float rv[4];
#pragma unroll
    for (int j = 0; j < 4; ++j) {
      int idx = (int)fmaf(o[j], inv_bw, 0.5f);
      idx = min(idx, 1000);
      float shift = fmaf(-((float)idx + 0.5f), bw, o[j]);
      float left  = s_pdf[idx];
      float right = s_pdf[idx + 1];
      float grad = (right - left) * inv_bw;
      float accu = fmaf(shift, grad, left);
      rv[j] = grad * __builtin_amdgcn_rcpf(accu);
    }
    v4f res = {rv[0], rv[1], rv[2], rv[3]};
    __builtin_nontemporal_store(res, &out4[k * TPB + tid]);
  }
}

// ---------------------------------------------------------------------------
extern "C" void kernel_launch(void* const* d_in, const int* in_sizes, int n_in,
                              void* d_out, int out_size, void* d_ws, size_t ws_size,
                              hipStream_t stream) {
  const float* sigmas     = (const float*)d_in[0];
  const float* omegas     = (const float*)d_in[1];
  const float* omega_grid = (const float*)d_in[2];
  // d_in[3] = ls (unused)
  const float* sine_terms = (const float*)d_in[4];
  float* out = (float*)d_out;

  const int B = in_sizes[0];  // 8192 -> one block per row

  const size_t tab_bytes   = (size_t)B * TAB_STRIDE * sizeof(float);      // 32 MB
  const size_t trans_bytes = (size_t)L_TERMS * TRANS_STRIDE * sizeof(float); // 404 KB

  if (ws_size >= tab_bytes + trans_bytes) {
    float* tabs   = (float*)d_ws;
    float* sine_t = (float*)((char*)d_ws + tab_bytes);
    transpose_sine<<<W_BINS, 128, 0, stream>>>(sine_terms, sine_t);
    build_tables<<<B, TPB, 0, stream>>>(sigmas, sine_t, tabs);
    igso3_gather<<<B, TPB, 0, stream>>>(sigmas, omegas, omega_grid, tabs, out);
  } else if (ws_size >= trans_bytes) {
    transpose_sine<<<W_BINS, 128, 0, stream>>>(sine_terms, (float*)d_ws);
    // no tabs space: fall back to combined kernel reading transposed table
    igso3_main_nt<<<B, TPB, 0, stream>>>(sigmas, omegas, omega_grid,
                                         sine_terms, out);
  } else {
    igso3_main_nt<<<B, TPB, 0, stream>>>(sigmas, omegas, omega_grid,
                                         sine_terms, out);
  }
}

// Round 7
// 261.966 us; speedup vs baseline: 1.0345x; 1.0053x over previous
//
#include <hip/hip_runtime.h>
#include <hip/hip_bf16.h>

// B=8192 rows, N=4096 omegas/row, W=1000 bins, L=101 Legendre terms.
// Exact simplifications (verified r3/r4):
//   * pdf normalization cancels in grad/pdf -> skipped
//   * sigma<=0.6 rows are pure elementwise -omega/sigma^2
//   * series terms beyond l=16 underflow for sigma>0.6 -> fixed L=17 unroll
// Round-7 single-variable test: r3/r4/r6 (combined, split+barrier,
// split+barrier-free) ALL land 79-84us with every pipe <20% busy and
// implied wave lifetime ~13us -- stalls invisible to VALU/LDS counters.
// The one constant across every ~80us variant: __builtin_nontemporal_store
// for all 131MB of output (bypasses L2 -> direct-HBM write path). fillBuffer
// with plain stores hits 6.7 TB/s on this device; we sustain 1.6 TB/s of
// writes. Theory: nt-store path has shallow outstanding-write capacity ->
// tail stores serialize at memory latency, inflating wave lifetime.
// CHANGE: plain stores everywhere. Everything else identical to r6.

#define L_TERMS 101
#define W_BINS 1000
#define N_COLS 4096
#define TPB 256
#define TRANS_STRIDE 1024   // padded transpose row stride
#define TAB_STRIDE 1024     // floats per pdf-table row in workspace
#define PAD_W 1004          // (fallback kernel only)
#define GRAD_T 0.6f
#define L_FIX 17            // fixed term count, exact for sigma > 0.6

typedef float v4f __attribute__((ext_vector_type(4)));

// ---------------------------------------------------------------------------
// Transpose sine_terms [1000][101] -> sine_t [101][1024] (padded)
__global__ __launch_bounds__(128) void transpose_sine(
    const float* __restrict__ sine, float* __restrict__ sine_t) {
  int w = blockIdx.x;   // 0..999
  int t = threadIdx.x;  // 0..127
  if (t < L_TERMS) sine_t[(size_t)t * TRANS_STRIDE + w] = sine[(size_t)w * L_TERMS + t];
}

// ---------------------------------------------------------------------------
// Kernel A: per series-row pdf table -> tabs[b][0..999] (aligned stores).
// Verified in r4.
__global__ __launch_bounds__(TPB, 6) void build_tables(
    const float* __restrict__ sigmas,
    const float* __restrict__ sine_t,   // [101][1024]
    float* __restrict__ tabs) {         // [B][1024]
  const int b = blockIdx.x;
  const float s = sigmas[b];
  if (s <= GRAD_T) return;              // gaussian row: no table needed

  const int tid = threadIdx.x;
  const int w0 = tid * 4;
  if (w0 >= W_BINS) return;

  float e[L_FIX];
  const float ns2 = -0.5f * s * s;
#pragma unroll
  for (int l = 0; l < L_FIX; ++l)
    e[l] = __expf(ns2 * (float)(l * (l + 1)));

  float acc[4] = {0.0f, 0.0f, 0.0f, 0.0f};
#pragma unroll
  for (int l = 0; l < L_FIX; ++l) {
    v4f sv = *(const v4f*)(sine_t + (size_t)l * TRANS_STRIDE + w0);
    acc[0] = fmaf(e[l], sv.x, acc[0]);
    acc[1] = fmaf(e[l], sv.y, acc[1]);
    acc[2] = fmaf(e[l], sv.z, acc[2]);
    acc[3] = fmaf(e[l], sv.w, acc[3]);
  }
  v4f r = {acc[0], acc[1], acc[2], acc[3]};
  *(v4f*)(tabs + (size_t)b * TAB_STRIDE + w0) = r;   // cached store: B reads it next
}

// ---------------------------------------------------------------------------
// Kernel B: barrier-free streamer. Each wave stages the 4KB table into its
// OWN LDS region; loads stay in flight through staging + gather.
// r7: plain stores (nt removed).
__global__ __launch_bounds__(TPB, 6) void igso3_gather(
    const float* __restrict__ sigmas,
    const float* __restrict__ omegas,
    const float* __restrict__ omega_grid,
    const float* __restrict__ tabs,
    float* __restrict__ out) {
  __shared__ float s_tab[4][TAB_STRIDE];   // wave-private 4KB tables

  const int tid = threadIdx.x;
  const int wv  = tid >> 6;    // wave 0..3
  const int ln  = tid & 63;    // lane
  const int b = blockIdx.x;
  const float s = sigmas[b];
  const bool ser = s > GRAD_T;

  const v4f* __restrict__ om4 = (const v4f*)(omegas + (size_t)b * N_COLS);
  v4f* __restrict__ out4 = (v4f*)(out + (size_t)b * N_COLS);

  // Table loads FIRST (oldest in vmem queue): the ds_write below waits only
  // on these (vmcnt(4)), leaving the om loads in flight.
  v4f tv[4];
  if (ser) {
    const float* tb = tabs + (size_t)b * TAB_STRIDE;
#pragma unroll
    for (int k = 0; k < 4; ++k) tv[k] = *(const v4f*)(tb + k * 256 + ln * 4);
  }

  v4f om[4];
#pragma unroll
  for (int k = 0; k < 4; ++k) om[k] = om4[k * TPB + tid];

  const float bw = omega_grid[1] - omega_grid[0];
  const float inv_bw = 1.0f / bw;

  if (!ser) {
    const float inv_s2 = __builtin_amdgcn_rcpf(s * s);
#pragma unroll
    for (int k = 0; k < 4; ++k) {
      out4[k * TPB + tid] = om[k] * (-inv_s2);
    }
    return;
  }

  // Wave-private staging: linear b128 writes, conflict-free. No barrier --
  // same-wave ds ordering via lgkmcnt only.
  float* mytab = s_tab[wv];
#pragma unroll
  for (int k = 0; k < 4; ++k) *(v4f*)(mytab + k * 256 + ln * 4) = tv[k];

#pragma unroll
  for (int k = 0; k < 4; ++k) {
    float o[4] = {om[k].x, om[k].y, om[k].z, om[k].w};
    float rv[4];
#pragma unroll
    for (int j = 0; j < 4; ++j) {
      // omega >= 0 -> int-cast == floor; idx in [0,1000]
      int idx = (int)fmaf(o[j], inv_bw, 0.5f);
      idx = min(idx, 1000);
      float shift = fmaf(-((float)idx + 0.5f), bw, o[j]);
      int il = max(idx - 1, 0);               // pdf_pad[idx]
      int ir = (idx >= 1000) ? 998 : idx;     // pdf_pad[idx+1]
      float left  = mytab[il];
      float right = mytab[ir];
      float grad = (right - left) * inv_bw;
      float accu = fmaf(shift, grad, left);
      rv[j] = grad * __builtin_amdgcn_rcpf(accu);
    }
    v4f res = {rv[0], rv[1], rv[2], rv[3]};
    out4[k * TPB + tid] = res;
  }
}

// ---------------------------------------------------------------------------
// Fallback (no workspace): r3-verified combined kernel, untransposed input.
__global__ __launch_bounds__(TPB, 6) void igso3_main_nt(
    const float* __restrict__ sigmas,
    const float* __restrict__ omegas,
    const float* __restrict__ omega_grid,
    const float* __restrict__ sine_src,  // [1000][101]
    float* __restrict__ out) {
  __shared__ float s_pdf[PAD_W];

  const int tid = threadIdx.x;
  const int b = blockIdx.x;

  const v4f* __restrict__ om4 = (const v4f*)(omegas + (size_t)b * N_COLS);
  v4f* __restrict__ out4 = (v4f*)(out + (size_t)b * N_COLS);

  v4f om[4];
#pragma unroll
  for (int k = 0; k < 4; ++k) om[k] = om4[k * TPB + tid];

  const float s = sigmas[b];
  const float bw = omega_grid[1] - omega_grid[0];
  const float inv_bw = 1.0f / bw;

  if (s <= GRAD_T) {
    const float inv_s2 = __builtin_amdgcn_rcpf(s * s);
#pragma unroll
    for (int k = 0; k < 4; ++k) {
      out4[k * TPB + tid] = om[k] * (-inv_s2);
    }
    return;
  }

  float e[L_FIX];
  const float ns2 = -0.5f * s * s;
#pragma unroll
  for (int l = 0; l < L_FIX; ++l) e[l] = __expf(ns2 * (float)(l * (l + 1)));

  const int w0 = tid * 4;
  float acc[4] = {0.0f, 0.0f, 0.0f, 0.0f};
  if (w0 < W_BINS) {
#pragma unroll
    for (int l = 0; l < L_FIX; ++l) {
#pragma unroll
      for (int j = 0; j < 4; ++j)
        acc[j] = fmaf(e[l], sine_src[(size_t)(w0 + j) * L_TERMS + l], acc[j]);
    }
#pragma unroll
    for (int j = 0; j < 4; ++j) s_pdf[w0 + 1 + j] = acc[j];
    if (tid == 0) s_pdf[0] = acc[0];
    if (w0 == 996) s_pdf[1001] = acc[2];
  }
  __syncthreads();

#pragma unroll
  for (int k = 0; k < 4; ++k) {
    float o[4] = {om[k].x, om[k].y, om[k].z, om[k].w};
    float rv[4];
#pragma unroll
    for (int j = 0; j < 4; ++j) {
      int idx = (int)fmaf(o[j], inv_bw, 0.5f);
      idx = min(idx, 1000);
      float shift = fmaf(-((float)idx + 0.5f), bw, o[j]);
      float left  = s_pdf[idx];
      float right = s_pdf[idx + 1];
      float grad = (right - left) * inv_bw;
      float accu = fmaf(shift, grad, left);
      rv[j] = grad * __builtin_amdgcn_rcpf(accu);
    }
    v4f res = {rv[0], rv[1], rv[2], rv[3]};
    out4[k * TPB + tid] = res;
  }
}

// ---------------------------------------------------------------------------
extern "C" void kernel_launch(void* const* d_in, const int* in_sizes, int n_in,
                              void* d_out, int out_size, void* d_ws, size_t ws_size,
                              hipStream_t stream) {
  const float* sigmas     = (const float*)d_in[0];
  const float* omegas     = (const float*)d_in[1];
  const float* omega_grid = (const float*)d_in[2];
  // d_in[3] = ls (unused)
  const float* sine_terms = (const float*)d_in[4];
  float* out = (float*)d_out;

  const int B = in_sizes[0];  // 8192 -> one block per row

  const size_t tab_bytes   = (size_t)B * TAB_STRIDE * sizeof(float);      // 32 MB
  const size_t trans_bytes = (size_t)L_TERMS * TRANS_STRIDE * sizeof(float); // 404 KB

  if (ws_size >= tab_bytes + trans_bytes) {
    float* tabs   = (float*)d_ws;
    float* sine_t = (float*)((char*)d_ws + tab_bytes);
    transpose_sine<<<W_BINS, 128, 0, stream>>>(sine_terms, sine_t);
    build_tables<<<B, TPB, 0, stream>>>(sigmas, sine_t, tabs);
    igso3_gather<<<B, TPB, 0, stream>>>(sigmas, omegas, omega_grid, tabs, out);
  } else {
    igso3_main_nt<<<B, TPB, 0, stream>>>(sigmas, omegas, omega_grid,
                                         sine_terms, out);
  }
}

// Round 9
// 261.675 us; speedup vs baseline: 1.0356x; 1.0011x over previous
//
#include <hip/hip_runtime.h>
#include <hip/hip_bf16.h>

// B=8192 rows, N=4096 omegas/row, W=1000 bins, L=101 Legendre terms.
// Exact simplifications (verified r3/r4/r7):
//   * pdf normalization cancels in grad/pdf -> skipped
//   * sigma<=0.6 rows are pure elementwise -omega/sigma^2
//   * series terms beyond l=16 underflow for sigma>0.6 -> fixed L=17 unroll
// Round-9 = round-8 theory with the r8 LDS-overrun bug fixed:
//   r8 shrank the wave-private table to 1004 floats but staged 1024/wave ->
//   cross-wave LDS stomp (absmax 7.7e5). Stride restored to 1024 (as the
//   passing r6/r7). Theory under test (unifies r1-r7): MLP was killed in
//   every prior variant -- r1/r3/r4 by the __syncthreads vmcnt(0) drain,
//   r6/r7 by the compiler register-minimizing to VGPR=24 (8 dwordx4 loads
//   need 32 data VGPRs -> serial memory chain, ~13us wave lifetime). Fix:
//   barrier-free structure + asm register pins so all 8 loads issue up
//   front and stay in flight. Gather uses contiguous-pair ds_read2_b32:
//   T[k]=p[k], T[1000]=p[998]; left=T[max(idx-1,0)], right=idx==0?left:T[idx].

#define L_TERMS 101
#define W_BINS 1000
#define N_COLS 4096
#define TPB 256
#define TRANS_STRIDE 1024   // padded transpose row stride
#define TAB_STRIDE 1024     // floats per pdf-table row in workspace
#define TAB_LDS 1024        // wave-private LDS table stride (staging writes 1024!)
#define PAD_W 1004          // (fallback kernel only)
#define GRAD_T 0.6f
#define L_FIX 17            // fixed term count, exact for sigma > 0.6

typedef float v4f __attribute__((ext_vector_type(4)));

#define KEEP4(x) asm volatile("" : "+v"(x))

// ---------------------------------------------------------------------------
// Transpose sine_terms [1000][101] -> sine_t [101][1024] (padded)
__global__ __launch_bounds__(128) void transpose_sine(
    const float* __restrict__ sine, float* __restrict__ sine_t) {
  int w = blockIdx.x;   // 0..999
  int t = threadIdx.x;  // 0..127
  if (t < L_TERMS) sine_t[(size_t)t * TRANS_STRIDE + w] = sine[(size_t)w * L_TERMS + t];
}

// ---------------------------------------------------------------------------
// Kernel A: per series-row pdf table -> tabs[b][0..999] (aligned stores).
// Verified in r4.
__global__ __launch_bounds__(TPB, 6) void build_tables(
    const float* __restrict__ sigmas,
    const float* __restrict__ sine_t,   // [101][1024]
    float* __restrict__ tabs) {         // [B][1024]
  const int b = blockIdx.x;
  const float s = sigmas[b];
  if (s <= GRAD_T) return;              // gaussian row: no table needed

  const int tid = threadIdx.x;
  const int w0 = tid * 4;
  if (w0 >= W_BINS) return;

  float e[L_FIX];
  const float ns2 = -0.5f * s * s;
#pragma unroll
  for (int l = 0; l < L_FIX; ++l)
    e[l] = __expf(ns2 * (float)(l * (l + 1)));

  float acc[4] = {0.0f, 0.0f, 0.0f, 0.0f};
#pragma unroll
  for (int l = 0; l < L_FIX; ++l) {
    v4f sv = *(const v4f*)(sine_t + (size_t)l * TRANS_STRIDE + w0);
    acc[0] = fmaf(e[l], sv.x, acc[0]);
    acc[1] = fmaf(e[l], sv.y, acc[1]);
    acc[2] = fmaf(e[l], sv.z, acc[2]);
    acc[3] = fmaf(e[l], sv.w, acc[3]);
  }
  v4f r = {acc[0], acc[1], acc[2], acc[3]};
  *(v4f*)(tabs + (size_t)b * TAB_STRIDE + w0) = r;   // cached store: B reads it next
}

// ---------------------------------------------------------------------------
// Kernel B: barrier-free streamer, register-pinned loads.
__global__ __launch_bounds__(TPB, 6) void igso3_gather(
    const float* __restrict__ sigmas,
    const float* __restrict__ omegas,
    const float* __restrict__ omega_grid,
    const float* __restrict__ tabs,
    float* __restrict__ out) {
  __shared__ float s_tab[4][TAB_LDS];   // wave-private 4KB tables (staging fills all 1024)

  const int tid = threadIdx.x;
  const int wv  = tid >> 6;    // wave 0..3
  const int ln  = tid & 63;    // lane
  const int b = blockIdx.x;
  const float s = sigmas[b];
  const bool ser = s > GRAD_T;

  const v4f* __restrict__ om4 = (const v4f*)(omegas + (size_t)b * N_COLS);
  v4f* __restrict__ out4 = (v4f*)(out + (size_t)b * N_COLS);

  // Issue ALL global loads up front; pins force concurrent liveness so the
  // compiler cannot register-minimize them back into a serial chain.
  v4f tv[4];
  if (ser) {
    const float* tb = tabs + (size_t)b * TAB_STRIDE;
#pragma unroll
    for (int k = 0; k < 4; ++k) tv[k] = *(const v4f*)(tb + k * 256 + ln * 4);
  }

  v4f om[4];
#pragma unroll
  for (int k = 0; k < 4; ++k) om[k] = om4[k * TPB + tid];

  if (ser) { KEEP4(tv[0]); KEEP4(tv[1]); KEEP4(tv[2]); KEEP4(tv[3]); }
  KEEP4(om[0]); KEEP4(om[1]); KEEP4(om[2]); KEEP4(om[3]);
  asm volatile("" ::: "memory");   // compiler-only fence: no load sinks below

  const float bw = omega_grid[1] - omega_grid[0];
  const float inv_bw = 1.0f / bw;

  if (!ser) {
    const float inv_s2 = __builtin_amdgcn_rcpf(s * s);
#pragma unroll
    for (int k = 0; k < 4; ++k) {
      out4[k * TPB + tid] = om[k] * (-inv_s2);
    }
    return;
  }

  // Wave-private staging: aligned b128 writes of T[0..1023] within OWN
  // region (stride 1024 -- r8's 1004-stride overran into the next wave's
  // table). No barrier: same-wave ds ordering via lgkmcnt only. The pad
  // write below is program-order AFTER the k=3 vector write that also
  // touches T[1000], and same-wave LDS ops complete in order -> T[1000]
  // ends as p[998].
  float* mytab = s_tab[wv];
#pragma unroll
  for (int k = 0; k < 4; ++k) *(v4f*)(mytab + k * 256 + ln * 4) = tv[k];
  if (ln == 57) mytab[1000] = tv[3].z;   // T[1000] = p[998] (pad for idx=1000)

#pragma unroll
  for (int k = 0; k < 4; ++k) {
    float o[4] = {om[k].x, om[k].y, om[k].z, om[k].w};
    float rv[4];
#pragma unroll
    for (int j = 0; j < 4; ++j) {
      // omega >= 0 -> int-cast == floor; idx in [0,1000]
      int idx = (int)fmaf(o[j], inv_bw, 0.5f);
      idx = min(idx, 1000);
      float shift = fmaf(-((float)idx + 0.5f), bw, o[j]);
      int bidx = max(idx - 1, 0);
      float l = mytab[bidx];           // ds_read2_b32 pair
      float r = mytab[bidx + 1];
      // pdf_pad semantics: left=p[max(idx-1,0)]; right=p[idx] for idx<1000,
      // p[998] for idx=1000 (=T[1000]); idx==0 -> right=p[0]=left.
      float right = (idx == 0) ? l : r;
      float grad = (right - l) * inv_bw;
      float accu = fmaf(shift, grad, l);
      rv[j] = grad * __builtin_amdgcn_rcpf(accu);
    }
    v4f res = {rv[0], rv[1], rv[2], rv[3]};
    out4[k * TPB + tid] = res;
  }
}

// ---------------------------------------------------------------------------
// Fallback (no workspace): r3-verified combined kernel, untransposed input.
__global__ __launch_bounds__(TPB, 6) void igso3_main_nt(
    const float* __restrict__ sigmas,
    const float* __restrict__ omegas,
    const float* __restrict__ omega_grid,
    const float* __restrict__ sine_src,  // [1000][101]
    float* __restrict__ out) {
  __shared__ float s_pdf[PAD_W];

  const int tid = threadIdx.x;
  const int b = blockIdx.x;

  const v4f* __restrict__ om4 = (const v4f*)(omegas + (size_t)b * N_COLS);
  v4f* __restrict__ out4 = (v4f*)(out + (size_t)b * N_COLS);

  v4f om[4];
#pragma unroll
  for (int k = 0; k < 4; ++k) om[k] = om4[k * TPB + tid];

  const float s = sigmas[b];
  const float bw = omega_grid[1] - omega_grid[0];
  const float inv_bw = 1.0f / bw;

  if (s <= GRAD_T) {
    const float inv_s2 = __builtin_amdgcn_rcpf(s * s);
#pragma unroll
    for (int k = 0; k < 4; ++k) {
      out4[k * TPB + tid] = om[k] * (-inv_s2);
    }
    return;
  }

  float e[L_FIX];
  const float ns2 = -0.5f * s * s;
#pragma unroll
  for (int l = 0; l < L_FIX; ++l) e[l] = __expf(ns2 * (float)(l * (l + 1)));

  const int w0 = tid * 4;
  float acc[4] = {0.0f, 0.0f, 0.0f, 0.0f};
  if (w0 < W_BINS) {
#pragma unroll
    for (int l = 0; l < L_FIX; ++l) {
#pragma unroll
      for (int j = 0; j < 4; ++j)
        acc[j] = fmaf(e[l], sine_src[(size_t)(w0 + j) * L_TERMS + l], acc[j]);
    }
#pragma unroll
    for (int j = 0; j < 4; ++j) s_pdf[w0 + 1 + j] = acc[j];
    if (tid == 0) s_pdf[0] = acc[0];
    if (w0 == 996) s_pdf[1001] = acc[2];
  }
  __syncthreads();

#pragma unroll
  for (int k = 0; k < 4; ++k) {
    float o[4] = {om[k].x, om[k].y, om[k].z, om[k].w};
    float rv[4];
#pragma unroll
    for (int j = 0; j < 4; ++j) {
      int idx = (int)fmaf(o[j], inv_bw, 0.5f);
      idx = min(idx, 1000);
      float shift = fmaf(-((float)idx + 0.5f), bw, o[j]);
      float left  = s_pdf[idx];
      float right = s_pdf[idx + 1];
      float grad = (right - left) * inv_bw;
      float accu = fmaf(shift, grad, left);
      rv[j] = grad * __builtin_amdgcn_rcpf(accu);
    }
    v4f res = {rv[0], rv[1], rv[2], rv[3]};
    out4[k * TPB + tid] = res;
  }
}

// ---------------------------------------------------------------------------
extern "C" void kernel_launch(void* const* d_in, const int* in_sizes, int n_in,
                              void* d_out, int out_size, void* d_ws, size_t ws_size,
                              hipStream_t stream) {
  const float* sigmas     = (const float*)d_in[0];
  const float* omegas     = (const float*)d_in[1];
  const float* omega_grid = (const float*)d_in[2];
  // d_in[3] = ls (unused)
  const float* sine_terms = (const float*)d_in[4];
  float* out = (float*)d_out;

  const int B = in_sizes[0];  // 8192 -> one block per row

  const size_t tab_bytes   = (size_t)B * TAB_STRIDE * sizeof(float);      // 32 MB
  const size_t trans_bytes = (size_t)L_TERMS * TRANS_STRIDE * sizeof(float); // 404 KB

  if (ws_size >= tab_bytes + trans_bytes) {
    float* tabs   = (float*)d_ws;
    float* sine_t = (float*)((char*)d_ws + tab_bytes);
    transpose_sine<<<W_BINS, 128, 0, stream>>>(sine_terms, sine_t);
    build_tables<<<B, TPB, 0, stream>>>(sigmas, sine_t, tabs);
    igso3_gather<<<B, TPB, 0, stream>>>(sigmas, omegas, omega_grid, tabs, out);
  } else {
    igso3_main_nt<<<B, TPB, 0, stream>>>(sigmas, omegas, omega_grid,
                                         sine_terms, out);
  }
}